// Round 1
// baseline (881.144 us; speedup 1.0000x reference)
//
#include <hip/hip_runtime.h>
#include <cstdint>
#include <cstddef>

#define NROWS 131072
#define DDIM  1024
#define LDIM  128
#define BSEG  64

typedef float f32x4 __attribute__((ext_vector_type(4)));
typedef short short8 __attribute__((ext_vector_type(8)));

__device__ inline unsigned short f2bf(float f) {
    union { float f; unsigned u; } x; x.f = f;
    unsigned u = x.u + 0x7fffu + ((x.u >> 16) & 1u);
    return (unsigned short)(u >> 16);
}

__device__ inline int lower_bound_dev(const int* __restrict__ arr, int n, int v) {
    int lo = 0, hi = n;
    while (lo < hi) { int mid = (lo + hi) >> 1; if (arr[mid] < v) lo = mid + 1; else hi = mid; }
    return lo;
}

// ---------------- K0: row norms (one wave per row) ----------------
__global__ void norm_kernel(const float* __restrict__ feat, float* __restrict__ inv_out) {
    int gw = (blockIdx.x * blockDim.x + threadIdx.x) >> 6;  // row id
    int lane = threadIdx.x & 63;
    const float4* row = (const float4*)(feat + (size_t)gw * DDIM);
    float ss = 0.f;
    #pragma unroll
    for (int j = 0; j < 4; ++j) {
        float4 v = row[lane + 64 * j];
        ss += v.x * v.x + v.y * v.y + v.z * v.z + v.w * v.w;
    }
    #pragma unroll
    for (int m = 1; m < 64; m <<= 1) ss += __shfl_xor(ss, m, 64);
    if (lane == 0) inv_out[gw] = 1.f / fmaxf(sqrtf(ss), 1e-12f);
}

// ---------------- K1: normalize + store + bf16 MFMA GEMM + gated score ----------------
// BM=64 rows/block, BN=256 (128 a-cols + 128 b-cols), BK=64, 4 waves.
__global__ __launch_bounds__(256, 3)
void gemm_kernel(const float* __restrict__ feat, const float* __restrict__ inv_norm,
                 const float* __restrict__ Wa, const float* __restrict__ ba,
                 const float* __restrict__ Wb, const float* __restrict__ bb,
                 const float* __restrict__ Wc, const float* __restrict__ bc,
                 float* __restrict__ nf_out, float* __restrict__ s_out)
{
    __shared__ __align__(16) char smem[40960];
    char* Abuf = smem;          // [64][64] bf16, XOR-swizzled rows, 8 KB
    char* Wbuf = smem + 8192;   // [256][64] bf16, XOR-swizzled rows, 32 KB
    float* ab  = (float*)smem;  // epilogue reuse: [64][132] f32 (33792 B)

    const int tid  = threadIdx.x;
    const int w    = tid >> 6;
    const int lane = tid & 63;
    const int rblk = blockIdx.x * 64;

    f32x4 acc[4][4];
    #pragma unroll
    for (int i = 0; i < 4; ++i)
        #pragma unroll
        for (int j = 0; j < 4; ++j)
            acc[i][j] = (f32x4){0.f, 0.f, 0.f, 0.f};

    // staging map: 4 threads per row, each 4 float4 chunks
    const int sr  = tid >> 2;   // 0..63
    const int sc4 = tid & 3;    // 0..3
    const float invA = inv_norm[rblk + sr];

    // compute-phase lane decomposition
    const int rA  = lane & 15;
    const int kl  = lane >> 4;
    const int swz = (lane & 7) << 4;

    for (int kt = 0; kt < 16; ++kt) {
        __syncthreads();
        // ---- stage A tile: 64 x 64 f32 -> normalize -> store f32 out + bf16 LDS
        #pragma unroll
        for (int j = 0; j < 4; ++j) {
            int col = (sc4 + j * 4) * 4;  // f32 col within BK tile
            size_t gidx = (size_t)(rblk + sr) * DDIM + kt * 64 + col;
            float4 v = *(const float4*)(feat + gidx);
            v.x *= invA; v.y *= invA; v.z *= invA; v.w *= invA;
            *(float4*)(nf_out + gidx) = v;
            ushort4 h;
            h.x = f2bf(v.x); h.y = f2bf(v.y); h.z = f2bf(v.z); h.w = f2bf(v.w);
            int byte = (sr * 128 + col * 2) ^ ((sr & 7) << 4);
            *(ushort4*)(Abuf + byte) = h;
        }
        // ---- stage W tile: 256 x 64 f32 -> bf16 LDS (L2-resident source)
        #pragma unroll
        for (int c = 0; c < 4; ++c) {
            int n = c * 64 + sr;
            const float* wrow = (n < LDIM) ? (Wa + (size_t)n * DDIM)
                                           : (Wb + (size_t)(n - LDIM) * DDIM);
            #pragma unroll
            for (int j = 0; j < 4; ++j) {
                int col = (sc4 + j * 4) * 4;
                float4 v = *(const float4*)(wrow + kt * 64 + col);
                ushort4 h;
                h.x = f2bf(v.x); h.y = f2bf(v.y); h.z = f2bf(v.z); h.w = f2bf(v.w);
                int byte = (n * 128 + col * 2) ^ ((n & 7) << 4);
                *(ushort4*)(Wbuf + byte) = h;
            }
        }
        __syncthreads();
        // ---- compute: wave w owns cols [w*64, w*64+64)
        #pragma unroll
        for (int kk = 0; kk < 2; ++kk) {
            int koff = ((kk * 64) + kl * 16) ^ swz;
            short8 af[4], bfr[4];
            #pragma unroll
            for (int mf = 0; mf < 4; ++mf)
                af[mf] = *(const short8*)(Abuf + (mf * 16 + rA) * 128 + koff);
            #pragma unroll
            for (int nf = 0; nf < 4; ++nf)
                bfr[nf] = *(const short8*)(Wbuf + (w * 64 + nf * 16 + rA) * 128 + koff);
            #pragma unroll
            for (int mf = 0; mf < 4; ++mf)
                #pragma unroll
                for (int nf = 0; nf < 4; ++nf)
                    acc[mf][nf] = __builtin_amdgcn_mfma_f32_16x16x32_bf16(
                        af[mf], bfr[nf], acc[mf][nf], 0, 0, 0);
        }
    }
    __syncthreads();

    // ---- epilogue: a = sigmoid(.+ba) (waves 0,1), p = a * tanh(.+bb) (waves 2,3)
    const float bcv = bc[0];
    if (w < 2) {
        #pragma unroll
        for (int mf = 0; mf < 4; ++mf)
            #pragma unroll
            for (int nf = 0; nf < 4; ++nf) {
                int n = w * 64 + nf * 16 + rA;   // 0..127
                float bias = ba[n];
                #pragma unroll
                for (int reg = 0; reg < 4; ++reg) {
                    int r = mf * 16 + kl * 4 + reg;
                    float v = acc[mf][nf][reg] + bias;
                    float a = 1.f / (1.f + __expf(-v));
                    ab[r * 132 + n] = a;
                }
            }
    }
    __syncthreads();
    if (w >= 2) {
        #pragma unroll
        for (int mf = 0; mf < 4; ++mf)
            #pragma unroll
            for (int nf = 0; nf < 4; ++nf) {
                int l = (w - 2) * 64 + nf * 16 + rA;  // 0..127
                float bias = bb[l];
                #pragma unroll
                for (int reg = 0; reg < 4; ++reg) {
                    int r = mf * 16 + kl * 4 + reg;
                    float v = acc[mf][nf][reg] + bias;
                    float bt = tanhf(v);
                    ab[r * 132 + l] *= bt;
                }
            }
    }
    __syncthreads();
    // ---- reduce over L=128 with Wc; 4 threads per row
    {
        int rho = tid >> 2, q = tid & 3;
        float sum = 0.f;
        #pragma unroll
        for (int j = 0; j < 32; ++j) {
            int l = q + 4 * j;
            sum += ab[rho * 132 + l] * Wc[l];
        }
        sum += __shfl_xor(sum, 1, 64);
        sum += __shfl_xor(sum, 2, 64);
        if (q == 0) s_out[rblk + rho] = sum + bcv;
    }
}

// ---------------- K2: per-segment softmax (batch is sorted) ----------------
__global__ void softmax_kernel(const int* __restrict__ batch, const float* __restrict__ s,
                               float* __restrict__ score_out) {
    int b = blockIdx.x;
    int tid = threadIdx.x;
    int start = lower_bound_dev(batch, NROWS, b);
    int end   = lower_bound_dev(batch, NROWS, b + 1);
    __shared__ float red[4];
    __shared__ float bm, bd;

    float m = -INFINITY;
    for (int i = start + tid; i < end; i += 256) m = fmaxf(m, s[i]);
    #pragma unroll
    for (int k = 1; k < 64; k <<= 1) m = fmaxf(m, __shfl_xor(m, k, 64));
    if ((tid & 63) == 0) red[tid >> 6] = m;
    __syncthreads();
    if (tid == 0) bm = fmaxf(fmaxf(red[0], red[1]), fmaxf(red[2], red[3]));
    __syncthreads();
    float M = bm;

    float sum = 0.f;
    for (int i = start + tid; i < end; i += 256) sum += __expf(s[i] - M);
    #pragma unroll
    for (int k = 1; k < 64; k <<= 1) sum += __shfl_xor(sum, k, 64);
    if ((tid & 63) == 0) red[tid >> 6] = sum;
    __syncthreads();
    if (tid == 0) bd = red[0] + red[1] + red[2] + red[3];
    __syncthreads();
    float invD = 1.f / bd;

    for (int i = start + tid; i < end; i += 256) score_out[i] = __expf(s[i] - M) * invD;
}

// ---------------- K3: out[b][d] = sum_i score[i]*nf[i][d], deterministic ----------------
__global__ void outsum_kernel(const int* __restrict__ batch, const float* __restrict__ score,
                              const float* __restrict__ nf, float* __restrict__ out) {
    int b  = blockIdx.x >> 2;
    int ch = blockIdx.x & 3;
    int t  = threadIdx.x;
    int d  = ch * 256 + (t & 255);
    int g  = t >> 8;
    int start = lower_bound_dev(batch, NROWS, b);
    int end   = lower_bound_dev(batch, NROWS, b + 1);
    float acc = 0.f;
    for (int i = start + g; i < end; i += 4)
        acc += score[i] * nf[(size_t)i * DDIM + d];
    __shared__ float red[1024];
    red[t] = acc;
    __syncthreads();
    if (t < 256)
        out[b * DDIM + ch * 256 + t] = red[t] + red[256 + t] + red[512 + t] + red[768 + t];
}

extern "C" void kernel_launch(void* const* d_in, const int* in_sizes, int n_in,
                              void* d_out, int out_size, void* d_ws, size_t ws_size,
                              hipStream_t stream) {
    const float* feat = (const float*)d_in[0];
    const int*   batch = (const int*)d_in[1];
    const float* Wa = (const float*)d_in[2];
    const float* ba = (const float*)d_in[3];
    const float* Wb = (const float*)d_in[4];
    const float* bb = (const float*)d_in[5];
    const float* Wc = (const float*)d_in[6];
    const float* bc = (const float*)d_in[7];

    float* out_seg   = (float*)d_out;                 // B*D = 65536
    float* score_out = out_seg + (size_t)BSEG * DDIM; // N = 131072
    float* nf_out    = score_out + NROWS;             // N*D

    float* ws_inv = (float*)d_ws;      // N floats
    float* ws_s   = ws_inv + NROWS;    // N floats

    norm_kernel<<<NROWS / 4, 256, 0, stream>>>(feat, ws_inv);
    gemm_kernel<<<NROWS / 64, 256, 0, stream>>>(feat, ws_inv, Wa, ba, Wb, bb, Wc, bc,
                                                nf_out, ws_s);
    softmax_kernel<<<BSEG, 256, 0, stream>>>(batch, ws_s, score_out);
    outsum_kernel<<<BSEG * 4, 1024, 0, stream>>>(batch, score_out, nf_out, out_seg);
}

// Round 2
// 479.106 us; speedup vs baseline: 1.8391x; 1.8391x over previous
//
#include <hip/hip_runtime.h>
#include <cstdint>
#include <cstddef>

#define NROWS 131072
#define DDIM  1024
#define LDIM  128
#define BSEG  64

typedef float f32x4 __attribute__((ext_vector_type(4)));
typedef short short8 __attribute__((ext_vector_type(8)));

#define FIXSCALE 9007199254740992.0   // 2^53

__device__ inline unsigned short f2bf(float f) {
    union { float f; unsigned u; } x; x.f = f;
    unsigned u = x.u + 0x7fffu + ((x.u >> 16) & 1u);
    return (unsigned short)(u >> 16);
}

__device__ inline int lower_bound_dev(const int* __restrict__ arr, int n, int v) {
    int lo = 0, hi = n;
    while (lo < hi) { int mid = (lo + hi) >> 1; if (arr[mid] < v) lo = mid + 1; else hi = mid; }
    return lo;
}

__device__ inline void gload_lds16(const void* g, void* l) {
    __builtin_amdgcn_global_load_lds(
        (const __attribute__((address_space(1))) unsigned int*)g,
        (__attribute__((address_space(3))) unsigned int*)l, 16, 0, 0);
}

// ---------------- W pre-convert: f32 -> bf16 in the swizzled LDS image layout ----------------
// wpre layout: [kt 0..15][32768 bytes], image byte = n*128 + ((c*2) ^ ((n&7)<<4))
__global__ void wconv_kernel(const float* __restrict__ Wa, const float* __restrict__ Wb,
                             unsigned short* __restrict__ wpre) {
    int n  = blockIdx.x;                 // 0..255
    int kt = threadIdx.x >> 4;           // 0..15
    int c6 = (threadIdx.x & 15) * 4;     // bf16 col within K-tile, 0..60
    const float* wrow = (n < LDIM) ? (Wa + (size_t)n * DDIM)
                                   : (Wb + (size_t)(n - LDIM) * DDIM);
    float4 v = *(const float4*)(wrow + kt * 64 + c6);
    ushort4 h;
    h.x = f2bf(v.x); h.y = f2bf(v.y); h.z = f2bf(v.z); h.w = f2bf(v.w);
    int byte = kt * 32768 + n * 128 + ((c6 * 2) ^ ((n & 7) << 4));
    *(ushort4*)((char*)wpre + byte) = h;
}

// ---------------- fused norm + GEMM + gated score ----------------
// BM=64 rows/block, 256 threads (4 waves), BK=64, double-buffered LDS.
// LDS: Abuf0 [0,8K) Abuf1 [8K,16K) Wbuf0 [16K,48K) Wbuf1 [48K,80K); epilogue reuses [0,33.8K)
__global__ __launch_bounds__(256, 2)
void gemm_kernel(const float* __restrict__ feat, const unsigned short* __restrict__ wpre,
                 const float* __restrict__ ba, const float* __restrict__ bb,
                 const float* __restrict__ Wc, const float* __restrict__ bc,
                 float* __restrict__ nf_out, float* __restrict__ s_out)
{
    __shared__ __align__(16) char smem[81920];
    float* ab = (float*)smem;

    const int tid  = threadIdx.x;
    const int w    = tid >> 6;
    const int lane = tid & 63;
    const int rblk = blockIdx.x * 64;
    const int sr   = tid >> 2;     // staging row 0..63
    const int sc4  = tid & 3;      // staging col-quad 0..3

    const float*  rowp  = feat + (size_t)(rblk + sr) * DDIM;
    const float4* rowp4 = (const float4*)rowp;

    // ---- phase 0: row sum-of-squares (reads full row once; L2 keeps it warm for the K-loop)
    float a0 = 0.f, a1 = 0.f, a2 = 0.f, a3 = 0.f;
    for (int t = 0; t < 64; t += 4) {
        float4 va = rowp4[sc4 + 4 * t];
        float4 vb = rowp4[sc4 + 4 * t + 4];
        float4 vc = rowp4[sc4 + 4 * t + 8];
        float4 vd = rowp4[sc4 + 4 * t + 12];
        a0 += va.x * va.x + va.y * va.y + va.z * va.z + va.w * va.w;
        a1 += vb.x * vb.x + vb.y * vb.y + vb.z * vb.z + vb.w * vb.w;
        a2 += vc.x * vc.x + vc.y * vc.y + vc.z * vc.z + vc.w * vc.w;
        a3 += vd.x * vd.x + vd.y * vd.y + vd.z * vd.z + vd.w * vd.w;
    }
    float ss = a0 + a1 + a2 + a3;
    ss += __shfl_xor(ss, 1, 64);
    ss += __shfl_xor(ss, 2, 64);
    const float invA = 1.f / fmaxf(sqrtf(ss), 1e-12f);

    f32x4 acc[4][4];
    #pragma unroll
    for (int i = 0; i < 4; ++i)
        #pragma unroll
        for (int j = 0; j < 4; ++j)
            acc[i][j] = (f32x4){0.f, 0.f, 0.f, 0.f};

    // compute-phase lane decomposition
    const int rA  = lane & 15;
    const int kl  = lane >> 4;
    const int swz = (lane & 7) << 4;

    const char* wsrc = (const char*)wpre;

    // ---- prologue: stage kt=0 into buffer 0
    {
        char* wdst = smem + 16384;
        #pragma unroll
        for (int q = 0; q < 8; ++q) {
            int ch = w * 8 + q;
            gload_lds16(wsrc + ch * 1024 + lane * 16, wdst + ch * 1024);
        }
        char* Abuf = smem;
        #pragma unroll
        for (int j = 0; j < 4; ++j) {
            int cf = sc4 + j * 4;              // float4 index in tile
            float4 v = rowp4[cf];
            v.x *= invA; v.y *= invA; v.z *= invA; v.w *= invA;
            *(float4*)(nf_out + (size_t)(rblk + sr) * DDIM + cf * 4) = v;
            ushort4 h;
            h.x = f2bf(v.x); h.y = f2bf(v.y); h.z = f2bf(v.z); h.w = f2bf(v.w);
            int byte = (sr * 128 + cf * 8) ^ ((sr & 7) << 4);
            *(ushort4*)(Abuf + byte) = h;
        }
    }
    __syncthreads();

    int cur = 0;
    for (int kt = 0; kt < 16; ++kt) {
        float4 av[4];
        if (kt < 15) {
            // issue next W tile (global_load_lds, no VALU) and next A f32 loads early
            char* wdst = smem + 16384 + (cur ^ 1) * 32768;
            const char* src = wsrc + (kt + 1) * 32768;
            #pragma unroll
            for (int q = 0; q < 8; ++q) {
                int ch = w * 8 + q;
                gload_lds16(src + ch * 1024 + lane * 16, wdst + ch * 1024);
            }
            #pragma unroll
            for (int j = 0; j < 4; ++j)
                av[j] = rowp4[(kt + 1) * 16 + sc4 + j * 4];
        }

        // ---- compute on current buffers
        {
            const char* Abuf = smem + cur * 8192;
            const char* Wbuf = smem + 16384 + cur * 32768;
            #pragma unroll
            for (int kk = 0; kk < 2; ++kk) {
                int koff = ((kk * 64) + kl * 16) ^ swz;
                short8 af[4], bfr[4];
                #pragma unroll
                for (int mf = 0; mf < 4; ++mf)
                    af[mf] = *(const short8*)(Abuf + (mf * 16 + rA) * 128 + koff);
                #pragma unroll
                for (int nf = 0; nf < 4; ++nf)
                    bfr[nf] = *(const short8*)(Wbuf + (w * 64 + nf * 16 + rA) * 128 + koff);
                #pragma unroll
                for (int mf = 0; mf < 4; ++mf)
                    #pragma unroll
                    for (int nf = 0; nf < 4; ++nf)
                        acc[mf][nf] = __builtin_amdgcn_mfma_f32_16x16x32_bf16(
                            af[mf], bfr[nf], acc[mf][nf], 0, 0, 0);
            }
        }

        if (kt < 15) {
            // process next A tile: normalize, store nf, convert, ds_write to other buffer
            char* Abuf = smem + (cur ^ 1) * 8192;
            #pragma unroll
            for (int j = 0; j < 4; ++j) {
                int cf = sc4 + j * 4;
                float4 v = av[j];
                v.x *= invA; v.y *= invA; v.z *= invA; v.w *= invA;
                *(float4*)(nf_out + (size_t)(rblk + sr) * DDIM + (kt + 1) * 64 + cf * 4) = v;
                ushort4 h;
                h.x = f2bf(v.x); h.y = f2bf(v.y); h.z = f2bf(v.z); h.w = f2bf(v.w);
                int byte = (sr * 128 + cf * 8) ^ ((sr & 7) << 4);
                *(ushort4*)(Abuf + byte) = h;
            }
        }
        __syncthreads();
        cur ^= 1;
    }

    // ---- epilogue: a = sigmoid(.+ba) (waves 0,1), p = a * tanh(.+bb) (waves 2,3)
    const float bcv = bc[0];
    if (w < 2) {
        #pragma unroll
        for (int mf = 0; mf < 4; ++mf)
            #pragma unroll
            for (int nf = 0; nf < 4; ++nf) {
                int n = w * 64 + nf * 16 + rA;   // 0..127
                float bias = ba[n];
                #pragma unroll
                for (int reg = 0; reg < 4; ++reg) {
                    int r = mf * 16 + kl * 4 + reg;
                    float v = acc[mf][nf][reg] + bias;
                    float a = 1.f / (1.f + __expf(-v));
                    ab[r * 132 + n] = a;
                }
            }
    }
    __syncthreads();
    if (w >= 2) {
        #pragma unroll
        for (int mf = 0; mf < 4; ++mf)
            #pragma unroll
            for (int nf = 0; nf < 4; ++nf) {
                int l = (w - 2) * 64 + nf * 16 + rA;  // 0..127
                float bias = bb[l];
                #pragma unroll
                for (int reg = 0; reg < 4; ++reg) {
                    int r = mf * 16 + kl * 4 + reg;
                    float v = acc[mf][nf][reg] + bias;
                    float bt = tanhf(v);
                    ab[r * 132 + l] *= bt;
                }
            }
    }
    __syncthreads();
    // ---- reduce over L=128 with Wc; 4 threads per row
    {
        int rho = tid >> 2, q = tid & 3;
        float sum = 0.f;
        #pragma unroll
        for (int j = 0; j < 32; ++j) {
            int l = q + 4 * j;
            sum += ab[rho * 132 + l] * Wc[l];
        }
        sum += __shfl_xor(sum, 1, 64);
        sum += __shfl_xor(sum, 2, 64);
        if (q == 0) s_out[rblk + rho] = sum + bcv;
    }
}

// ---------------- softmax per segment, in place on the score slot ----------------
__global__ void softmax_kernel(const int* __restrict__ batch, float* __restrict__ score) {
    int b = blockIdx.x;
    int tid = threadIdx.x;
    int start = lower_bound_dev(batch, NROWS, b);
    int end   = lower_bound_dev(batch, NROWS, b + 1);
    __shared__ float red[4];
    __shared__ float bm, bd;

    float m = -INFINITY;
    for (int i = start + tid; i < end; i += 256) m = fmaxf(m, score[i]);
    #pragma unroll
    for (int k = 1; k < 64; k <<= 1) m = fmaxf(m, __shfl_xor(m, k, 64));
    if ((tid & 63) == 0) red[tid >> 6] = m;
    __syncthreads();
    if (tid == 0) bm = fmaxf(fmaxf(red[0], red[1]), fmaxf(red[2], red[3]));
    __syncthreads();
    float M = bm;

    float sum = 0.f;
    for (int i = start + tid; i < end; i += 256) sum += __expf(score[i] - M);
    #pragma unroll
    for (int k = 1; k < 64; k <<= 1) sum += __shfl_xor(sum, k, 64);
    if ((tid & 63) == 0) red[tid >> 6] = sum;
    __syncthreads();
    if (tid == 0) bd = red[0] + red[1] + red[2] + red[3];
    __syncthreads();
    float invD = 1.f / bd;

    for (int i = start + tid; i < end; i += 256)
        score[i] = __expf(score[i] - M) * invD;
}

// ---------------- outsum stage 1: 16 row-slices per segment, int64 fixed-point atomics ----------------
__global__ void outsum1_kernel(const int* __restrict__ batch, const float* __restrict__ score,
                               const float* __restrict__ nf, unsigned long long* __restrict__ acc64) {
    int b  = blockIdx.x >> 4;
    int sl = blockIdx.x & 15;
    int t  = threadIdx.x;          // float4 column 0..255
    int start = lower_bound_dev(batch, NROWS, b);
    int end   = lower_bound_dev(batch, NROWS, b + 1);
    float4 a = {0.f, 0.f, 0.f, 0.f};
    for (int i = start + sl; i < end; i += 16) {
        float s = score[i];
        float4 v = *(const float4*)(nf + (size_t)i * DDIM + t * 4);
        a.x += s * v.x; a.y += s * v.y; a.z += s * v.z; a.w += s * v.w;
    }
    unsigned long long* dst = acc64 + (size_t)b * DDIM + t * 4;
    atomicAdd(&dst[0], (unsigned long long)(long long)((double)a.x * FIXSCALE));
    atomicAdd(&dst[1], (unsigned long long)(long long)((double)a.y * FIXSCALE));
    atomicAdd(&dst[2], (unsigned long long)(long long)((double)a.z * FIXSCALE));
    atomicAdd(&dst[3], (unsigned long long)(long long)((double)a.w * FIXSCALE));
}

__global__ void outsum2_kernel(const unsigned long long* __restrict__ acc64,
                               float* __restrict__ out) {
    int i = blockIdx.x * 256 + threadIdx.x;
    out[i] = (float)((double)(long long)acc64[i] * (1.0 / FIXSCALE));
}

extern "C" void kernel_launch(void* const* d_in, const int* in_sizes, int n_in,
                              void* d_out, int out_size, void* d_ws, size_t ws_size,
                              hipStream_t stream) {
    const float* feat  = (const float*)d_in[0];
    const int*   batch = (const int*)d_in[1];
    const float* Wa = (const float*)d_in[2];
    const float* ba = (const float*)d_in[3];
    const float* Wb = (const float*)d_in[4];
    const float* bb = (const float*)d_in[5];
    const float* Wc = (const float*)d_in[6];
    const float* bc = (const float*)d_in[7];

    float* out_seg = (float*)d_out;                  // B*D
    float* score   = out_seg + (size_t)BSEG * DDIM;  // N (pre-softmax s, then softmax in place)
    float* nf      = score + NROWS;                  // N*D

    unsigned short*     wpre  = (unsigned short*)d_ws;                       // 512 KB
    unsigned long long* acc64 = (unsigned long long*)((char*)d_ws + 524288); // 512 KB

    hipMemsetAsync(acc64, 0, (size_t)BSEG * DDIM * 8, stream);
    wconv_kernel<<<256, 256, 0, stream>>>(Wa, Wb, wpre);
    gemm_kernel<<<NROWS / 64, 256, 0, stream>>>(feat, wpre, ba, bb, Wc, bc, nf, score);
    softmax_kernel<<<BSEG, 256, 0, stream>>>(batch, score);
    outsum1_kernel<<<BSEG * 16, 256, 0, stream>>>(batch, score, nf, acc64);
    outsum2_kernel<<<BSEG * DDIM / 256, 256, 0, stream>>>(acc64, out_seg);
}